// Round 2
// baseline (44.145 us; speedup 1.0000x reference)
//
#include <hip/hip_runtime.h>

// LIF neuron scan: membrane = 0.9*m + x_t; spike = m > 0.5; reset on spike.
// x: [B=128, T=256, F=1024] fp32, out: same shape fp32 (0.0/1.0 spikes).
// One thread per (b, f-pair): walks T sequentially, float2 loads/stores.
// __fmul_rn/__fadd_rn prevent fma contraction -> bit-exact vs numpy ref
// (a 1-ulp membrane difference near 0.5 flips a spike => absmax 1.0).

#define T_STEPS 256
#define F_DIM   1024
#define F2      (F_DIM / 2)

__global__ __launch_bounds__(256) void FastLIFNeuron_33784212750507_kernel(
    const float* __restrict__ x, float* __restrict__ out) {
    const int tid = blockIdx.x * blockDim.x + threadIdx.x;   // 0 .. B*F2-1
    const int b   = tid >> 9;          // / F2 (=512)
    const int f2  = tid & (F2 - 1);    // % F2

    const float2* __restrict__ xp =
        reinterpret_cast<const float2*>(x) + (size_t)b * T_STEPS * F2 + f2;
    float2* __restrict__ op =
        reinterpret_cast<float2*>(out) + (size_t)b * T_STEPS * F2 + f2;

    float m0 = 0.0f, m1 = 0.0f;

    #pragma unroll 16
    for (int t = 0; t < T_STEPS; ++t) {
        const float2 xv = xp[(size_t)t * F2];
        // membrane = 0.9*m + x, mul-then-add in rn (NOT fma) to match numpy
        m0 = __fadd_rn(__fmul_rn(0.9f, m0), xv.x);
        m1 = __fadd_rn(__fmul_rn(0.9f, m1), xv.y);
        const float s0 = (m0 > 0.5f) ? 1.0f : 0.0f;
        const float s1 = (m1 > 0.5f) ? 1.0f : 0.0f;
        // reset: m*(1-spike) is exactly 0 when spiking, exactly m otherwise
        m0 = (m0 > 0.5f) ? 0.0f : m0;
        m1 = (m1 > 0.5f) ? 0.0f : m1;
        op[(size_t)t * F2] = make_float2(s0, s1);
    }
}

extern "C" void kernel_launch(void* const* d_in, const int* in_sizes, int n_in,
                              void* d_out, int out_size, void* d_ws, size_t ws_size,
                              hipStream_t stream) {
    const float* x = (const float*)d_in[0];
    float* out = (float*)d_out;

    const int total = in_sizes[0];                 // B*T*F = 33554432
    const int B = total / (T_STEPS * F_DIM);       // 128
    const int threads = B * F2;                    // 65536
    const int block = 256;
    const int grid = (threads + block - 1) / block;  // 256 blocks

    FastLIFNeuron_33784212750507_kernel<<<grid, block, 0, stream>>>(x, out);
}